// Round 13
// baseline (238.644 us; speedup 1.0000x reference)
//
#include <hip/hip_runtime.h>

// Multihead self-attention with 3-scale relative positional embeddings.
// B=4, S=1024, D=512, H=8, HD=64.  Outputs: out (4,1024,512) f32, attn (4,8,1024,1024) f32.
//
// Skew algebra (verified round 1):
//   Srel_q[i,j]  = q[i] . Er_q[1023 + j - i]
//   Srel_b[i,j]  = q[i] . Er_b[255 + (j>>2) - (i>>2)]
//   Srel_r[i,j]  = q[i] . Er_r[63  + (j>>4) - (i>>4)]
//
// Round-13: round-9 structure (verified correct; sustained 3.24 TB/s when
// BW-bound) with ONE change: non-temporal stores -> normal stores (R9's nt
// caused FETCH~WRITE~340MB RMW line fills; normal stores use L2 write-back).

typedef float f32x4 __attribute__((ext_vector_type(4)));
typedef short s16x8 __attribute__((ext_vector_type(8)));
typedef short s16x4 __attribute__((ext_vector_type(4)));
typedef __bf16 bf16x8 __attribute__((ext_vector_type(8)));

static __device__ __forceinline__ short f2bf(float f) {
    return __builtin_bit_cast(short, (__bf16)f);
}
static __device__ __forceinline__ float bf2f(short s) {
    union { unsigned u; float f; } v;
    v.u = ((unsigned)(unsigned short)s) << 16;
    return v.f;
}
static __device__ __forceinline__ f32x4 MM(s16x8 a, s16x8 b, f32x4 c) {
    return __builtin_amdgcn_mfma_f32_16x16x32_bf16(
        __builtin_bit_cast(bf16x8, a), __builtin_bit_cast(bf16x8, b), c, 0, 0, 0);
}

// ---------------------------------------------------------------------------
// K0: one-shot f32 -> bf16 conversion of all reused operands.
// ---------------------------------------------------------------------------
struct CvtArgs {
    const float* src[9];
    short* dst[9];
    unsigned n[9];
};

__global__ __launch_bounds__(256) void convert_kernel(CvtArgs a) {
    const int ai = blockIdx.y;
    const unsigned n = a.n[ai];
    const float* __restrict__ s = a.src[ai];
    short* __restrict__ d = a.dst[ai];
    const unsigned stride = gridDim.x * 256 * 8;
    for (unsigned base = (blockIdx.x * 256 + threadIdx.x) * 8; base < n; base += stride) {
        f32x4 v0 = *(const f32x4*)(s + base);
        f32x4 v1 = *(const f32x4*)(s + base + 4);
        s16x8 o;
        o[0] = f2bf(v0[0]); o[1] = f2bf(v0[1]); o[2] = f2bf(v0[2]); o[3] = f2bf(v0[3]);
        o[4] = f2bf(v1[0]); o[5] = f2bf(v1[1]); o[6] = f2bf(v1[2]); o[7] = f2bf(v1[3]);
        *(s16x8*)(d + base) = o;
    }
}

// ---------------------------------------------------------------------------
// K1: QKV projections, 64x64 wave tiles, swapped operands -> vector b64 stores.
// ---------------------------------------------------------------------------
__global__ __launch_bounds__(128, 2) void proj_kernel(
    const short* __restrict__ queryb, const short* __restrict__ keyb, const short* __restrict__ valueb,
    const short* __restrict__ Wqb, const float* __restrict__ bq,
    const short* __restrict__ Wkb, const float* __restrict__ bk,
    const short* __restrict__ Wvb, const float* __restrict__ bv,
    short* __restrict__ qb, short* __restrict__ kb, short* __restrict__ vT)
{
    const int tid = threadIdx.x;
    const int wid = tid >> 6, lane = tid & 63;
    const int l15 = lane & 15, grp = lane >> 4;
    const int gid = blockIdx.x * 2 + wid;     // 0..1535
    const int z = gid >> 9;                   // 0,1,2
    const int r = gid & 511;

    const short *Am, *Bm;
    const float* bias;
    int a0, b0;
    if (z == 0)      { Am = Wqb;    Bm = queryb; bias = bq; a0 = (r >> 6) * 64; b0 = (r & 63) * 64; }
    else if (z == 1) { Am = Wkb;    Bm = keyb;   bias = bk; a0 = (r >> 6) * 64; b0 = (r & 63) * 64; }
    else             { Am = valueb; Bm = Wvb;    bias = bv; a0 = (r >> 3) * 64; b0 = (r & 7) * 64; }

    f32x4 acc[4][4];
    #pragma unroll
    for (int i = 0; i < 4; ++i)
        #pragma unroll
        for (int j = 0; j < 4; ++j)
            acc[i][j] = f32x4{0.f, 0.f, 0.f, 0.f};

    const short* arow0 = Am + (size_t)(a0 + l15) * 512 + grp * 8;
    const short* brow0 = Bm + (size_t)(b0 + l15) * 512 + grp * 8;

    s16x8 aA[4], bA[4], aB[4], bB[4];
    #pragma unroll
    for (int i = 0; i < 4; ++i) {
        aA[i] = *(const s16x8*)(arow0 + (size_t)i * 16 * 512);
        bA[i] = *(const s16x8*)(brow0 + (size_t)i * 16 * 512);
    }
    for (int kk = 0; kk < 512; kk += 32) {
        const int kn = kk + 32;
        if (kn < 512) {
            #pragma unroll
            for (int i = 0; i < 4; ++i) {
                aB[i] = *(const s16x8*)(arow0 + (size_t)i * 16 * 512 + kn);
                bB[i] = *(const s16x8*)(brow0 + (size_t)i * 16 * 512 + kn);
            }
        }
        #pragma unroll
        for (int i = 0; i < 4; ++i)
            #pragma unroll
            for (int j = 0; j < 4; ++j)
                acc[i][j] = MM(aA[i], bA[j], acc[i][j]);
        #pragma unroll
        for (int i = 0; i < 4; ++i) { aA[i] = aB[i]; bA[i] = bB[i]; }
    }

    if (z < 2) {
        short* dst = (z == 0) ? qb : kb;
        #pragma unroll
        for (int i = 0; i < 4; ++i) {
            const int f0 = a0 + i * 16 + grp * 4;
            const f32x4 bv4 = *(const f32x4*)&bias[f0];
            const int h = f0 >> 6, d0 = f0 & 63;
            #pragma unroll
            for (int j = 0; j < 4; ++j) {
                const int srow = b0 + j * 16 + l15;
                const int bb = srow >> 10, sl = srow & 1023;
                s16x4 o;
                #pragma unroll
                for (int g = 0; g < 4; ++g)
                    o[g] = f2bf(acc[i][j][g] + bv4[g]);
                *(s16x4*)&dst[(size_t)((bb * 8 + h) * 1024 + sl) * 64 + d0] = o;
            }
        }
    } else {
        #pragma unroll
        for (int j = 0; j < 4; ++j) {
            const int n = b0 + j * 16 + l15;
            const float bval = bias[n];
            const int h = n >> 6, d = n & 63;
            #pragma unroll
            for (int i = 0; i < 4; ++i) {
                const int s0 = a0 + i * 16 + grp * 4;
                const int bb = s0 >> 10, sl = s0 & 1023;
                s16x4 o;
                #pragma unroll
                for (int g = 0; g < 4; ++g)
                    o[g] = f2bf(acc[i][j][g] + bval);
                *(s16x4*)&vT[(size_t)((bb * 8 + h) * 64 + d) * 1024 + sl] = o;
            }
        }
    }
}

// ---------------------------------------------------------------------------
// K2: fused relative attention, 2 blocks/CU (round-9 structure).
// Grid 512 x 512thr; block = (b,h, 64-row chunk), 4 strips of 16 rows.
// Thread (wid,grp,l15): P[i=l15][j = wid*128 + t*16 + grp*4 + g].
// LDS 77312B: two 32896B regions alternating RQ2/PS+PACC roles; RB2/RR2;
// RSUM strip-parity buffered.  3 syncthreads/strip.
// ---------------------------------------------------------------------------
__global__ __launch_bounds__(512, 4) void attn_kernel(
    const short* __restrict__ Eqb, const short* __restrict__ Ebb, const short* __restrict__ Errb,
    const short* __restrict__ qb, const short* __restrict__ kb, const short* __restrict__ vT,
    float* __restrict__ out, float* __restrict__ attn)
{
    __shared__ __align__(16) char smem[77312];

    const int tid = threadIdx.x;
    const int wid = tid >> 6, lane = tid & 63;
    const int l15 = lane & 15, grp = lane >> 4;

    // XCD-aware bijective swizzle: 512 blocks, XCD x -> data-bids 64x..64x+63.
    const int orig = blockIdx.x;
    const int bid = (orig & 7) * 64 + (orig >> 3);

    const int bh = bid >> 4;                 // b*8+h
    const int chunk = bid & 15;              // 64-row chunk
    const int h = bh & 7;
    const int b = bh >> 3;

    const short* EqH = Eqb  + (size_t)h * 2047 * 64;
    const short* EbH = Ebb  + (size_t)h * 511 * 64;
    const short* ErH = Errb + (size_t)h * 127 * 64;
    const short* qbH = qb + (size_t)bh * 1024 * 64;
    const short* kbH = kb + (size_t)bh * 1024 * 64;
    const short* vTH = vT + (size_t)bh * 64 * 1024;

    short* RB2 = (short*)(smem + 65792);
    short* RR2 = (short*)(smem + 74112);

    // ---- table builder: RQ2 -> given region with per-wave col ownership ----
    auto buildT = [&](int i0s, char* regRQ, s16x8 q0, s16x8 q1) {
        short* RQ2 = (short*)regRQ;
        const int qbase = 1008 - i0s;
        {
            auto ldq = [&](int cs, s16x8& e0, s16x8& e1) {
                int erow = qbase + wid * 128 + cs * 16 + l15;
                if (erow > 2046) erow = 2046;
                const short* ep = EqH + (size_t)erow * 64 + grp * 8;
                e0 = *(const s16x8*)ep;
                e1 = *(const s16x8*)(ep + 32);
            };
            s16x8 A0, A1, B0, B1;
            ldq(0, A0, A1);
            ldq(1, B0, B1);
            for (int cs = 0; cs < 9; ++cs) {
                f32x4 a = f32x4{0.f, 0.f, 0.f, 0.f};
                a = MM(q0, A0, a);
                a = MM(q1, A1, a);
                A0 = B0; A1 = B1;
                if (cs < 8) ldq(cs + 2, B0, B1);
                const int c = wid * 128 + cs * 16 + l15;
                #pragma unroll
                for (int g = 0; g < 4; ++g) {
                    const int ii = grp * 4 + g;
                    const int j = c - 15 + ii;
                    if (j >= wid * 128 && j < wid * 128 + 128 && j < 1024)
                        RQ2[ii * 1028 + j] = f2bf(a[g]);
                }
            }
        }
        const int bbase = 252 - (i0s >> 2);
        {
            auto ldb = [&](int cs, s16x8& e0, s16x8& e1) {
                int erow = bbase + cs * 16 + l15;
                if (erow > 510) erow = 510;
                const short* ep = EbH + (size_t)erow * 64 + grp * 8;
                e0 = *(const s16x8*)ep;
                e1 = *(const s16x8*)(ep + 32);
            };
            s16x8 A0, A1, B0, B1;
            ldb(wid, A0, A1);
            ldb(wid + 8, B0, B1);
            for (int cs = wid; cs < 17; cs += 8) {
                f32x4 a = f32x4{0.f, 0.f, 0.f, 0.f};
                a = MM(q0, A0, a);
                a = MM(q1, A1, a);
                A0 = B0; A1 = B1;
                ldb(cs + 16, B0, B1);
                const int c = cs * 16 + l15;
                const int jq = c - 3 + grp;
                if (jq >= 0 && jq < 256) {
                    #pragma unroll
                    for (int g = 0; g < 4; ++g)
                        RB2[(grp * 4 + g) * 260 + jq] = f2bf(a[g]);
                }
            }
        }
        const int rbase = 63 - (i0s >> 4);
        if (wid < 4) {
            const int c = wid * 16 + l15;
            const short* ep = ErH + (size_t)(rbase + c) * 64 + grp * 8;
            s16x8 e0 = *(const s16x8*)ep;
            s16x8 e1 = *(const s16x8*)(ep + 32);
            f32x4 a = f32x4{0.f, 0.f, 0.f, 0.f};
            a = MM(q0, e0, a);
            a = MM(q1, e1, a);
            #pragma unroll
            for (int g = 0; g < 4; ++g)
                RR2[(grp * 4 + g) * 68 + c] = f2bf(a[g]);
        }
    };

    // ---- prologue: q(strip0), build tables for strip 0 into region A ----
    const int i00 = chunk * 64;
    s16x8 qA0 = *(const s16x8*)(qbH + (size_t)(i00 + l15) * 64 + grp * 8);
    s16x8 qA1 = *(const s16x8*)(qbH + (size_t)(i00 + l15) * 64 + 32 + grp * 8);
    buildT(i00, smem, qA0, qA1);
    __syncthreads();

    const float SC = 0.125f * 1.4426950408889634f;   // 1/sqrt(64) * log2(e)
    const int swz = (l15 & 3) << 5;                  // PS col XOR swizzle

    for (int s = 0; s < 4; ++s) {
        const int i0 = i00 + s * 16;
        char* tabR = smem + ((s & 1) ? 32896 : 0);   // RQ2(s); PACC overlays
        char* psR  = smem + ((s & 1) ? 0 : 32896);   // PS(s); RQ2(s+1) target
        short* RQ2c = (short*)tabR;
        short* PSc  = (short*)psR;
        float* RSUMp = (float*)(smem + 76288) + (s & 1) * 128;

        // ---- K fragment loads (L2-hot) + next-q prefetch ----
        s16x8 kf[8][2];
        #pragma unroll
        for (int t = 0; t < 8; ++t) {
            const short* kp = kbH + (size_t)(wid * 128 + t * 16 + l15) * 64 + grp * 8;
            kf[t][0] = *(const s16x8*)kp;
            kf[t][1] = *(const s16x8*)(kp + 32);
        }
        s16x8 qn0, qn1;
        if (s < 3) {
            qn0 = *(const s16x8*)(qbH + (size_t)(i0 + 16 + l15) * 64 + grp * 8);
            qn1 = *(const s16x8*)(qbH + (size_t)(i0 + 16 + l15) * 64 + 32 + grp * 8);
        }

        // ---- loop1: QK^T (swapped) + vector gathers + exp2 -> p ----
        f32x4 p[8];
        #pragma unroll
        for (int t = 0; t < 8; ++t) {
            f32x4 a = f32x4{0.f, 0.f, 0.f, 0.f};
            a = MM(kf[t][0], qA0, a);
            a = MM(kf[t][1], qA1, a);
            const int jb2 = wid * 128 + t * 16 + grp * 4;
            s16x4 gq4 = *(const s16x4*)&RQ2c[l15 * 1028 + jb2];
            const float rb = bf2f(RB2[l15 * 260 + wid * 32 + t * 4 + grp]);
            const float rr = bf2f(RR2[l15 * 68 + wid * 8 + t]);
            const float add = rb + rr;
            f32x4 pe;
            #pragma unroll
            for (int g = 0; g < 4; ++g)
                pe[g] = __builtin_amdgcn_exp2f((a[g] + bf2f(gq4[g]) + add) * SC);
            p[t] = pe;
        }

        // ---- rowsum partial -> RSUM[parity] ----
        float part = 0.f;
        #pragma unroll
        for (int t = 0; t < 8; ++t)
            #pragma unroll
            for (int g = 0; g < 4; ++g)
                part += p[t][g];
        part += __shfl_xor(part, 16, 64);
        part += __shfl_xor(part, 32, 64);
        if (lane < 16) RSUMp[lane * 8 + wid] = part;

        // ---- stage unnormalized bf16 P into own PS slice (swizzled b64) ----
        #pragma unroll
        for (int t = 0; t < 8; ++t) {
            const int col = (wid * 128 + t * 16 + grp * 4) ^ swz;
            s16x4 o;
            #pragma unroll
            for (int g = 0; g < 4; ++g) o[g] = f2bf(p[t][g]);
            *(s16x4*)&PSc[l15 * 1028 + col] = o;
        }
        __syncthreads();                              // BAR1: RSUM+PS visible; RQ2 dead

        // ---- V fragment loads ----
        s16x8 vreg[16];
        #pragma unroll
        for (int dvt = 0; dvt < 4; ++dvt)
            #pragma unroll
            for (int kc = 0; kc < 4; ++kc)
                vreg[dvt * 4 + kc] = *(const s16x8*)(vTH + (size_t)(dvt * 16 + l15) * 1024
                                                     + wid * 128 + kc * 32 + grp * 8);

        // ---- rinv + bfrag reads (own PS slice, BEFORE buildT overwrites it) ----
        float rinv;
        {
            f32x4 s0 = *(const f32x4*)&RSUMp[l15 * 8];
            f32x4 s1 = *(const f32x4*)&RSUMp[l15 * 8 + 4];
            rinv = 1.0f / (s0[0] + s0[1] + s0[2] + s0[3] + s1[0] + s1[1] + s1[2] + s1[3]);
        }
        s16x8 bfrag[4];
        #pragma unroll
        for (int kc = 0; kc < 4; ++kc) {
            const int col = (wid * 128 + kc * 32 + grp * 8) ^ swz;
            bfrag[kc] = *(const s16x8*)&PSc[l15 * 1028 + col];
        }

        // ---- build next strip's tables into PS region (own col slice only) ----
        if (s < 3) buildT(i0 + 16, psR, qn0, qn1);

        // ---- attn store from regs (normal stores; L2 write-back) ----
        {
            float* arow = attn + (size_t)(bh * 1024 + i0 + l15) * 1024;
            #pragma unroll
            for (int t = 0; t < 8; ++t) {
                f32x4 o = p[t] * rinv;
                *(f32x4*)&arow[wid * 128 + t * 16 + grp * 4] = o;
            }
        }

        // ---- PV (bfrag regs x vreg) -> PACC over dead RQ2 region (swizzled) ----
        f32x4 acc[4];
        #pragma unroll
        for (int dvt = 0; dvt < 4; ++dvt) acc[dvt] = f32x4{0.f, 0.f, 0.f, 0.f};
        #pragma unroll
        for (int kc = 0; kc < 4; ++kc)
            #pragma unroll
            for (int dvt = 0; dvt < 4; ++dvt)
                acc[dvt] = MM(vreg[dvt * 4 + kc], bfrag[kc], acc[dvt]);
        float* PACC = (float*)tabR;
        #pragma unroll
        for (int dvt = 0; dvt < 4; ++dvt)
            *(f32x4*)&PACC[wid * 1028 + l15 * 64 + ((dvt * 16 + grp * 4) ^ ((l15 & 7) << 3))] = acc[dvt];
        __syncthreads();                              // BAR2: PACC + tables visible

        // ---- out-reduce (waves 0-3) -> normal store ----
        if (tid < 256) {
            const int i = tid >> 4, dvq = tid & 15;
            f32x4 o = f32x4{0.f, 0.f, 0.f, 0.f};
            #pragma unroll
            for (int w = 0; w < 8; ++w)
                o += *(const f32x4*)&PACC[w * 1028 + i * 64 + ((dvq * 4) ^ ((i & 7) << 3))];
            f32x4 s0 = *(const f32x4*)&RSUMp[i * 8];
            f32x4 s1 = *(const f32x4*)&RSUMp[i * 8 + 4];
            const float ri = 1.0f / (s0[0] + s0[1] + s0[2] + s0[3] + s1[0] + s1[1] + s1[2] + s1[3]);
            o *= ri;
            *(f32x4*)&out[(size_t)(b * 1024 + i0 + i) * 512 + h * 64 + dvq * 4] = o;
        }
        __syncthreads();                              // BAR3: PACC dead -> reusable as PS(s+1)

        if (s < 3) { qA0 = qn0; qA1 = qn1; }
    }
}

// ---------------------------------------------------------------------------
extern "C" void kernel_launch(void* const* d_in, const int* in_sizes, int n_in,
                              void* d_out, int out_size, void* d_ws, size_t ws_size,
                              hipStream_t stream)
{
    const float* query = (const float*)d_in[0];
    const float* key   = (const float*)d_in[1];
    const float* value = (const float*)d_in[2];
    const float* Wq = (const float*)d_in[3];
    const float* bq = (const float*)d_in[4];
    const float* Wk = (const float*)d_in[5];
    const float* bk = (const float*)d_in[6];
    const float* Wv = (const float*)d_in[7];
    const float* bv = (const float*)d_in[8];
    const float* Eq = (const float*)d_in[9];
    const float* Eb = (const float*)d_in[10];
    const float* Er = (const float*)d_in[11];

    float* out  = (float*)d_out;
    float* attn = out + (size_t)4 * 1024 * 512;

    short* qb     = (short*)d_ws;
    short* kb     = qb     + 2097152;
    short* vT     = kb     + 2097152;
    short* queryb = vT     + 2097152;
    short* keyb   = queryb + 2097152;
    short* valueb = keyb   + 2097152;
    short* Wqb    = valueb + 2097152;
    short* Wkb    = Wqb    + 262144;
    short* Wvb    = Wkb    + 262144;
    short* Eqb    = Wvb    + 262144;
    short* Ebb    = Eqb    + 1048064;   // 8*2047*64
    short* Errb   = Ebb    + 261632;    // 8*511*64

    CvtArgs a;
    a.src[0] = query; a.dst[0] = queryb; a.n[0] = 2097152;
    a.src[1] = key;   a.dst[1] = keyb;   a.n[1] = 2097152;
    a.src[2] = value; a.dst[2] = valueb; a.n[2] = 2097152;
    a.src[3] = Wq;    a.dst[3] = Wqb;    a.n[3] = 262144;
    a.src[4] = Wk;    a.dst[4] = Wkb;    a.n[4] = 262144;
    a.src[5] = Wv;    a.dst[5] = Wvb;    a.n[5] = 262144;
    a.src[6] = Eq;    a.dst[6] = Eqb;    a.n[6] = 1048064;
    a.src[7] = Eb;    a.dst[7] = Ebb;    a.n[7] = 261632;
    a.src[8] = Er;    a.dst[8] = Errb;   a.n[8] = 65024;

    convert_kernel<<<dim3(128, 9), 256, 0, stream>>>(a);
    proj_kernel<<<768, 128, 0, stream>>>(queryb, keyb, valueb,
                                         Wqb, bq, Wkb, bk, Wvb, bv, qb, kb, vT);
    attn_kernel<<<512, 512, 0, stream>>>(Eqb, Ebb, Errb, qb, kb, vT, out, attn);
}

// Round 14
// 236.359 us; speedup vs baseline: 1.0097x; 1.0097x over previous
//
#include <hip/hip_runtime.h>

// Multihead self-attention with 3-scale relative positional embeddings.
// B=4, S=1024, D=512, H=8, HD=64.  Outputs: out (4,1024,512) f32, attn (4,8,1024,1024) f32.
//
// Skew algebra (verified round 1):
//   Srel_q[i,j]  = q[i] . Er_q[1023 + j - i]
//   Srel_b[i,j]  = q[i] . Er_b[255 + (j>>2) - (i>>2)]
//   Srel_r[i,j]  = q[i] . Er_r[63  + (j>>4) - (i>>4)]
//
// Round-14: R7 structure (best verified: attn 91.8us) + producer/consumer
// wave split: 8 compute waves (R7 pipeline minus attn store) + 4 writer
// waves issuing 1KB-contiguous attn stores that float across strips.
// lgkm-only barriers (compute waves have no big global stores now).

typedef float f32x4 __attribute__((ext_vector_type(4)));
typedef short s16x8 __attribute__((ext_vector_type(8)));
typedef short s16x4 __attribute__((ext_vector_type(4)));
typedef __bf16 bf16x8 __attribute__((ext_vector_type(8)));

static __device__ __forceinline__ short f2bf(float f) {
    return __builtin_bit_cast(short, (__bf16)f);
}
static __device__ __forceinline__ float bf2f(short s) {
    union { unsigned u; float f; } v;
    v.u = ((unsigned)(unsigned short)s) << 16;
    return v.f;
}
static __device__ __forceinline__ f32x4 MM(s16x8 a, s16x8 b, f32x4 c) {
    return __builtin_amdgcn_mfma_f32_16x16x32_bf16(
        __builtin_bit_cast(bf16x8, a), __builtin_bit_cast(bf16x8, b), c, 0, 0, 0);
}
#define KEEP(x) asm volatile("" : "+v"(x))
// lgkm-only barrier: drains LDS ops, leaves global stores/loads in flight.
#define BARL() asm volatile("s_waitcnt lgkmcnt(0)\n\ts_barrier" ::: "memory")

// ---------------------------------------------------------------------------
// K0: one-shot f32 -> bf16 conversion of all reused operands.
// ---------------------------------------------------------------------------
struct CvtArgs {
    const float* src[9];
    short* dst[9];
    unsigned n[9];
};

__global__ __launch_bounds__(256) void convert_kernel(CvtArgs a) {
    const int ai = blockIdx.y;
    const unsigned n = a.n[ai];
    const float* __restrict__ s = a.src[ai];
    short* __restrict__ d = a.dst[ai];
    const unsigned stride = gridDim.x * 256 * 8;
    for (unsigned base = (blockIdx.x * 256 + threadIdx.x) * 8; base < n; base += stride) {
        f32x4 v0 = *(const f32x4*)(s + base);
        f32x4 v1 = *(const f32x4*)(s + base + 4);
        s16x8 o;
        o[0] = f2bf(v0[0]); o[1] = f2bf(v0[1]); o[2] = f2bf(v0[2]); o[3] = f2bf(v0[3]);
        o[4] = f2bf(v1[0]); o[5] = f2bf(v1[1]); o[6] = f2bf(v1[2]); o[7] = f2bf(v1[3]);
        *(s16x8*)(d + base) = o;
    }
}

// ---------------------------------------------------------------------------
// K1: QKV projections, 64x64 wave tiles, swapped operands -> vector b64 stores.
// ---------------------------------------------------------------------------
__global__ __launch_bounds__(128, 2) void proj_kernel(
    const short* __restrict__ queryb, const short* __restrict__ keyb, const short* __restrict__ valueb,
    const short* __restrict__ Wqb, const float* __restrict__ bq,
    const short* __restrict__ Wkb, const float* __restrict__ bk,
    const short* __restrict__ Wvb, const float* __restrict__ bv,
    short* __restrict__ qb, short* __restrict__ kb, short* __restrict__ vT)
{
    const int tid = threadIdx.x;
    const int wid = tid >> 6, lane = tid & 63;
    const int l15 = lane & 15, grp = lane >> 4;
    const int gid = blockIdx.x * 2 + wid;     // 0..1535
    const int z = gid >> 9;                   // 0,1,2
    const int r = gid & 511;

    const short *Am, *Bm;
    const float* bias;
    int a0, b0;
    if (z == 0)      { Am = Wqb;    Bm = queryb; bias = bq; a0 = (r >> 6) * 64; b0 = (r & 63) * 64; }
    else if (z == 1) { Am = Wkb;    Bm = keyb;   bias = bk; a0 = (r >> 6) * 64; b0 = (r & 63) * 64; }
    else             { Am = valueb; Bm = Wvb;    bias = bv; a0 = (r >> 3) * 64; b0 = (r & 7) * 64; }

    f32x4 acc[4][4];
    #pragma unroll
    for (int i = 0; i < 4; ++i)
        #pragma unroll
        for (int j = 0; j < 4; ++j)
            acc[i][j] = f32x4{0.f, 0.f, 0.f, 0.f};

    const short* arow0 = Am + (size_t)(a0 + l15) * 512 + grp * 8;
    const short* brow0 = Bm + (size_t)(b0 + l15) * 512 + grp * 8;

    s16x8 aA[4], bA[4], aB[4], bB[4];
    #pragma unroll
    for (int i = 0; i < 4; ++i) {
        aA[i] = *(const s16x8*)(arow0 + (size_t)i * 16 * 512);
        bA[i] = *(const s16x8*)(brow0 + (size_t)i * 16 * 512);
    }
    for (int kk = 0; kk < 512; kk += 32) {
        const int kn = kk + 32;
        if (kn < 512) {
            #pragma unroll
            for (int i = 0; i < 4; ++i) {
                aB[i] = *(const s16x8*)(arow0 + (size_t)i * 16 * 512 + kn);
                bB[i] = *(const s16x8*)(brow0 + (size_t)i * 16 * 512 + kn);
            }
        }
        #pragma unroll
        for (int i = 0; i < 4; ++i)
            #pragma unroll
            for (int j = 0; j < 4; ++j)
                acc[i][j] = MM(aA[i], bA[j], acc[i][j]);
        #pragma unroll
        for (int i = 0; i < 4; ++i) { aA[i] = aB[i]; bA[i] = bB[i]; }
    }

    if (z < 2) {
        short* dst = (z == 0) ? qb : kb;
        #pragma unroll
        for (int i = 0; i < 4; ++i) {
            const int f0 = a0 + i * 16 + grp * 4;
            const f32x4 bv4 = *(const f32x4*)&bias[f0];
            const int h = f0 >> 6, d0 = f0 & 63;
            #pragma unroll
            for (int j = 0; j < 4; ++j) {
                const int srow = b0 + j * 16 + l15;
                const int bb = srow >> 10, sl = srow & 1023;
                s16x4 o;
                #pragma unroll
                for (int g = 0; g < 4; ++g)
                    o[g] = f2bf(acc[i][j][g] + bv4[g]);
                *(s16x4*)&dst[(size_t)((bb * 8 + h) * 1024 + sl) * 64 + d0] = o;
            }
        }
    } else {
        #pragma unroll
        for (int j = 0; j < 4; ++j) {
            const int n = b0 + j * 16 + l15;
            const float bval = bias[n];
            const int h = n >> 6, d = n & 63;
            #pragma unroll
            for (int i = 0; i < 4; ++i) {
                const int s0 = a0 + i * 16 + grp * 4;
                const int bb = s0 >> 10, sl = s0 & 1023;
                s16x4 o;
                #pragma unroll
                for (int g = 0; g < 4; ++g)
                    o[g] = f2bf(acc[i][j][g] + bval);
                *(s16x4*)&vT[(size_t)((bb * 8 + h) * 64 + d) * 1024 + sl] = o;
            }
        }
    }
}

// ---------------------------------------------------------------------------
// K2: persistent fused relative attention (R7 structure + writer waves).
// Grid 256 x 768thr (12 waves: 8 compute + 4 writer).
// Block = (b,h, 128-row chunk), 8 strips of 16 rows.
// Compute thread (wid,grp,l15): P[i=l15][j = wid*128 + t*16 + grp*4 + g].
// LDS 155520B:
//   RQ2 x2 [16][1028] bf16 @ 0 / 32896
//   RB2 x2 [16][260]  bf16 @ 65792 / 74112
//   RR2 x2 [16][68]   bf16 @ 82432 / 84608
//   PS      [16][1028] bf16 @ 86784  (XOR-swizzled cols, unnormalized P)
//   PACC    [8][16][68] f32 @ 119680
//   RSUM x2 [16][8] f32     @ 154496 / 155008  (512B each, parity)
// ---------------------------------------------------------------------------
__global__ __launch_bounds__(768, 3) void attn_kernel(
    const short* __restrict__ Eqb, const short* __restrict__ Ebb, const short* __restrict__ Errb,
    const short* __restrict__ qb, const short* __restrict__ kb, const short* __restrict__ vT,
    float* __restrict__ out, float* __restrict__ attn)
{
    __shared__ __align__(16) char smem[155520];
    short* PS   = (short*)(smem + 86784);
    float* PACC = (float*)(smem + 119680);

    const int tid = threadIdx.x;
    const int wid = tid >> 6, lane = tid & 63;
    const int l15 = lane & 15, grp = lane >> 4;
    const bool isC = (wid < 8);

    // XCD-aware bijective swizzle (256 blocks, %8==0): XCD x -> 4 whole bh.
    const int orig = blockIdx.x;
    const int bid = (orig & 7) * 32 + (orig >> 3);

    const int bh = bid >> 3;                 // b*8+h
    const int chunk = bid & 7;               // 128-row chunk
    const int h = bh & 7;
    const int b = bh >> 3;

    const short* EqH = Eqb  + (size_t)h * 2047 * 64;
    const short* EbH = Ebb  + (size_t)h * 511 * 64;
    const short* ErH = Errb + (size_t)h * 127 * 64;
    const short* qbH = qb + (size_t)bh * 1024 * 64;
    const short* kbH = kb + (size_t)bh * 1024 * 64;
    const short* vTH = vT + (size_t)bh * 64 * 1024;

    // ---- table builder (compute waves only) ----
    auto buildT = [&](int i0s, int bb01, s16x8 q0, s16x8 q1) {
        short* RQ2 = (short*)(smem + bb01 * 32896);
        short* RB2 = (short*)(smem + 65792 + bb01 * 8320);
        short* RR2 = (short*)(smem + 82432 + bb01 * 2176);
        const int qbase = 1008 - i0s;
        {
            auto ldq = [&](int cs, s16x8& e0, s16x8& e1) {
                int erow = qbase + cs * 16 + l15; if (erow > 2046) erow = 2046;
                const short* ep = EqH + (size_t)erow * 64 + grp * 8;
                e0 = *(const s16x8*)ep;
                e1 = *(const s16x8*)(ep + 32);
            };
            s16x8 A0, A1, B0, B1, C0, C1;
            ldq(wid, A0, A1);
            ldq(wid + 8, B0, B1);
            ldq(wid + 16, C0, C1);
            for (int cs = wid; cs < 65; cs += 8) {
                f32x4 a = f32x4{0.f, 0.f, 0.f, 0.f};
                a = MM(q0, A0, a);
                a = MM(q1, A1, a);
                A0 = B0; A1 = B1; B0 = C0; B1 = C1;
                ldq(cs + 24, C0, C1);             // clamped; tail loads unused
                const int c = cs * 16 + l15;
                #pragma unroll
                for (int g = 0; g < 4; ++g) {
                    const int ii = grp * 4 + g;
                    const int j = c - 15 + ii;
                    if (j >= 0 && j < 1024) RQ2[ii * 1028 + j] = f2bf(a[g]);
                }
            }
        }
        const int bbase = 252 - (i0s >> 2);
        {
            auto ldb = [&](int cs, s16x8& e0, s16x8& e1) {
                int erow = bbase + cs * 16 + l15; if (erow > 510) erow = 510;
                const short* ep = EbH + (size_t)erow * 64 + grp * 8;
                e0 = *(const s16x8*)ep;
                e1 = *(const s16x8*)(ep + 32);
            };
            s16x8 A0, A1, B0, B1;
            ldb(wid, A0, A1);
            ldb(wid + 8, B0, B1);
            for (int cs = wid; cs < 17; cs += 8) {
                f32x4 a = f32x4{0.f, 0.f, 0.f, 0.f};
                a = MM(q0, A0, a);
                a = MM(q1, A1, a);
                A0 = B0; A1 = B1;
                ldb(cs + 16, B0, B1);
                const int c = cs * 16 + l15;
                const int jq = c - 3 + grp;
                if (jq >= 0 && jq < 256) {
                    #pragma unroll
                    for (int g = 0; g < 4; ++g)
                        RB2[(grp * 4 + g) * 260 + jq] = f2bf(a[g]);
                }
            }
        }
        const int rbase = 63 - (i0s >> 4);
        if (wid < 4) {
            const int c = wid * 16 + l15;
            const short* ep = ErH + (size_t)(rbase + c) * 64 + grp * 8;
            s16x8 e0 = *(const s16x8*)ep;
            s16x8 e1 = *(const s16x8*)(ep + 32);
            f32x4 a = f32x4{0.f, 0.f, 0.f, 0.f};
            a = MM(q0, e0, a);
            a = MM(q1, e1, a);
            #pragma unroll
            for (int g = 0; g < 4; ++g)
                RR2[(grp * 4 + g) * 68 + c] = f2bf(a[g]);
        }
    };

    // ---- prologue (compute waves): q(strip0), K/V fragments, tables(0) ----
    const int i00 = chunk * 128;
    s16x8 qA0, qA1, kf[8][2], vreg[16];
    if (isC) {
        qA0 = *(const s16x8*)(qbH + (size_t)(i00 + l15) * 64 + grp * 8);
        qA1 = *(const s16x8*)(qbH + (size_t)(i00 + l15) * 64 + 32 + grp * 8);
        #pragma unroll
        for (int t = 0; t < 8; ++t) {
            const short* kp = kbH + (size_t)(wid * 128 + t * 16 + l15) * 64 + grp * 8;
            kf[t][0] = *(const s16x8*)kp;
            kf[t][1] = *(const s16x8*)(kp + 32);
        }
        #pragma unroll
        for (int dvt = 0; dvt < 4; ++dvt)
            #pragma unroll
            for (int kc = 0; kc < 4; ++kc)
                vreg[dvt * 4 + kc] = *(const s16x8*)(vTH + (size_t)(dvt * 16 + l15) * 1024
                                                     + wid * 128 + kc * 32 + grp * 8);
        buildT(i00, 0, qA0, qA1);
    }
    BARL();

    const float SC = 0.125f * 1.4426950408889634f;   // 1/sqrt(64) * log2(e)
    const int swz = (l15 & 3) << 5;                  // PS col XOR swizzle (row=l15)

    for (int s = 0; s < 8; ++s) {
        const int cur = s & 1;
        const int i0 = chunk * 128 + s * 16;
        float* RSUMc = (float*)(smem + 154496 + cur * 512);

        s16x8 qn0, qn1;
        if (isC) {
            #pragma unroll
            for (int t = 0; t < 8; ++t) { KEEP(kf[t][0]); KEEP(kf[t][1]); }
            #pragma unroll
            for (int z = 0; z < 16; ++z) KEEP(vreg[z]);

            short* RQ2c = (short*)(smem + cur * 32896);
            short* RB2c = (short*)(smem + 65792 + cur * 8320);
            short* RR2c = (short*)(smem + 82432 + cur * 2176);

            // prefetch next strip's q
            if (s < 7) {
                qn0 = *(const s16x8*)(qbH + (size_t)(i0 + 16 + l15) * 64 + grp * 8);
                qn1 = *(const s16x8*)(qbH + (size_t)(i0 + 16 + l15) * 64 + 32 + grp * 8);
            }

            // ---- QK^T (swapped) + gathers + exp2 -> p (unnormalized) ----
            f32x4 p[8];
            #pragma unroll
            for (int t = 0; t < 8; ++t) {
                f32x4 a = f32x4{0.f, 0.f, 0.f, 0.f};
                a = MM(kf[t][0], qA0, a);
                a = MM(kf[t][1], qA1, a);
                const int jb2 = wid * 128 + t * 16 + grp * 4;
                s16x4 gq4 = *(const s16x4*)&RQ2c[l15 * 1028 + jb2];
                const float rb = bf2f(RB2c[l15 * 260 + wid * 32 + t * 4 + grp]);
                const float rr = bf2f(RR2c[l15 * 68 + wid * 8 + t]);
                const float add = rb + rr;
                f32x4 pe;
                #pragma unroll
                for (int g = 0; g < 4; ++g)
                    pe[g] = __builtin_amdgcn_exp2f((a[g] + bf2f(gq4[g]) + add) * SC);
                p[t] = pe;
            }

            // ---- rowsum partial -> RSUM[parity] ----
            float part = 0.f;
            #pragma unroll
            for (int t = 0; t < 8; ++t)
                #pragma unroll
                for (int g = 0; g < 4; ++g)
                    part += p[t][g];
            part += __shfl_xor(part, 16, 64);
            part += __shfl_xor(part, 32, 64);
            if (lane < 16) RSUMc[lane * 8 + wid] = part;

            // ---- stage unnormalized bf16 P (vector b64, swizzled cols) ----
            #pragma unroll
            for (int t = 0; t < 8; ++t) {
                const int col = (wid * 128 + t * 16 + grp * 4) ^ swz;
                s16x4 o;
                #pragma unroll
                for (int g = 0; g < 4; ++g) o[g] = f2bf(p[t][g]);
                *(s16x4*)&PS[l15 * 1028 + col] = o;
            }
        }
        BARL();                                    // BAR1: PS + RSUM visible

        if (isC) {
            // ---- build next strip's tables (overlaps PV + writer stores) ----
            if (s < 7) buildT(i0 + 16, cur ^ 1, qn0, qn1);

            // ---- PV from own-wave PS + register V ----
            f32x4 acc[4];
            #pragma unroll
            for (int dvt = 0; dvt < 4; ++dvt) acc[dvt] = f32x4{0.f, 0.f, 0.f, 0.f};
            #pragma unroll
            for (int kc = 0; kc < 4; ++kc) {
                const int col = (wid * 128 + kc * 32 + grp * 8) ^ swz;
                s16x8 bfrag = *(const s16x8*)&PS[l15 * 1028 + col];
                #pragma unroll
                for (int dvt = 0; dvt < 4; ++dvt)
                    acc[dvt] = MM(vreg[dvt * 4 + kc], bfrag, acc[dvt]);
            }
            #pragma unroll
            for (int dvt = 0; dvt < 4; ++dvt)
                *(f32x4*)&PACC[(wid * 16 + l15) * 68 + dvt * 16 + grp * 4] = acc[dvt];
        } else {
            // ---- writer waves: attn f32 stores, 1KB contiguous, no drain ----
            const int ww = wid - 8;                // 0..3
            #pragma unroll
            for (int k = 0; k < 4; ++k) {
                const int r = ww * 4 + k;          // row 0..15
                f32x4 s0 = *(const f32x4*)&RSUMc[r * 8];
                f32x4 s1 = *(const f32x4*)&RSUMc[r * 8 + 4];
                const float ri = 1.0f / (s0[0] + s0[1] + s0[2] + s0[3]
                                         + s1[0] + s1[1] + s1[2] + s1[3]);
                float* arow = attn + (size_t)(bh * 1024 + i0 + r) * 1024;
                const int rswz = (r & 3) << 5;
                #pragma unroll
                for (int pass = 0; pass < 4; ++pass) {
                    const int col = pass * 256 + lane * 4;
                    s16x4 v4 = *(const s16x4*)&PS[r * 1028 + (col ^ rswz)];
                    f32x4 o;
                    o[0] = bf2f(v4[0]) * ri; o[1] = bf2f(v4[1]) * ri;
                    o[2] = bf2f(v4[2]) * ri; o[3] = bf2f(v4[3]) * ri;
                    *(f32x4*)(arow + col) = o;     // floats across strips
                }
            }
        }
        BARL();                                    // BAR2: PACC + tables visible

        if (isC) {
            // ---- out-reduce (waves 0-3) ----
            if (tid < 256) {
                const int i = tid >> 4, dvq = tid & 15;
                f32x4 o = f32x4{0.f, 0.f, 0.f, 0.f};
                #pragma unroll
                for (int w = 0; w < 8; ++w)
                    o += *(const f32x4*)&PACC[(w * 16 + i) * 68 + dvq * 4];
                f32x4 s0 = *(const f32x4*)&RSUMc[i * 8];
                f32x4 s1 = *(const f32x4*)&RSUMc[i * 8 + 4];
                const float ri = 1.0f / (s0[0] + s0[1] + s0[2] + s0[3]
                                         + s1[0] + s1[1] + s1[2] + s1[3]);
                o *= ri;
                *(f32x4*)&out[(size_t)(b * 1024 + i0 + i) * 512 + h * 64 + dvq * 4] = o;
            }
            if (s < 7) { qA0 = qn0; qA1 = qn1; }
        }
    }
}

// ---------------------------------------------------------------------------
extern "C" void kernel_launch(void* const* d_in, const int* in_sizes, int n_in,
                              void* d_out, int out_size, void* d_ws, size_t ws_size,
                              hipStream_t stream)
{
    const float* query = (const float*)d_in[0];
    const float* key   = (const float*)d_in[1];
    const float* value = (const float*)d_in[2];
    const float* Wq = (const float*)d_in[3];
    const float* bq = (const float*)d_in[4];
    const float* Wk = (const float*)d_in[5];
    const float* bk = (const float*)d_in[6];
    const float* Wv = (const float*)d_in[7];
    const float* bv = (const float*)d_in[8];
    const float* Eq = (const float*)d_in[9];
    const float* Eb = (const float*)d_in[10];
    const float* Er = (const float*)d_in[11];

    float* out  = (float*)d_out;
    float* attn = out + (size_t)4 * 1024 * 512;

    short* qb     = (short*)d_ws;
    short* kb     = qb     + 2097152;
    short* vT     = kb     + 2097152;
    short* queryb = vT     + 2097152;
    short* keyb   = queryb + 2097152;
    short* valueb = keyb   + 2097152;
    short* Wqb    = valueb + 2097152;
    short* Wkb    = Wqb    + 262144;
    short* Wvb    = Wkb    + 262144;
    short* Eqb    = Wvb    + 262144;
    short* Ebb    = Eqb    + 1048064;   // 8*2047*64
    short* Errb   = Ebb    + 261632;    // 8*511*64

    CvtArgs a;
    a.src[0] = query; a.dst[0] = queryb; a.n[0] = 2097152;
    a.src[1] = key;   a.dst[1] = keyb;   a.n[1] = 2097152;
    a.src[2] = value; a.dst[2] = valueb; a.n[2] = 2097152;
    a.src[3] = Wq;    a.dst[3] = Wqb;    a.n[3] = 262144;
    a.src[4] = Wk;    a.dst[4] = Wkb;    a.n[4] = 262144;
    a.src[5] = Wv;    a.dst[5] = Wvb;    a.n[5] = 262144;
    a.src[6] = Eq;    a.dst[6] = Eqb;    a.n[6] = 1048064;
    a.src[7] = Eb;    a.dst[7] = Ebb;    a.n[7] = 261632;
    a.src[8] = Er;    a.dst[8] = Errb;   a.n[8] = 65024;

    convert_kernel<<<dim3(128, 9), 256, 0, stream>>>(a);
    proj_kernel<<<768, 128, 0, stream>>>(queryb, keyb, valueb,
                                         Wqb, bq, Wkb, bk, Wvb, bv, qb, kb, vT);
    attn_kernel<<<256, 768, 0, stream>>>(Eqb, Ebb, Errb, qb, kb, vT, out, attn);
}

// Round 15
// 131.970 us; speedup vs baseline: 1.8083x; 1.7910x over previous
//
#include <hip/hip_runtime.h>

// Multihead self-attention with 3-scale relative positional embeddings.
// B=4, S=1024, D=512, H=8, HD=64.  Outputs: out (4,1024,512) f32, attn (4,8,1024,1024) f32.
//
// Skew algebra (verified round 1):
//   Srel_q[i,j]  = q[i] . Er_q[1023 + j - i]
//   Srel_b[i,j]  = q[i] . Er_b[255 + (j>>2) - (i>>2)]
//   Srel_r[i,j]  = q[i] . Er_r[63  + (j>>4) - (i>>4)]
//
// Round-15: R7 (best verified: attn 91.8us, total 129.5us) + two local fixes:
//  (1) RSUM parity buffers non-overlapping (stride 512B; removes latent race)
//  (2) attn store from PS as 1KB-contiguous row segments (was 64B segments),
//      inside the same barrier bracket (R13/R14 lesson: never decouple the
//      write stream from the compute window -> L2 thrash).

typedef float f32x4 __attribute__((ext_vector_type(4)));
typedef short s16x8 __attribute__((ext_vector_type(8)));
typedef short s16x4 __attribute__((ext_vector_type(4)));
typedef __bf16 bf16x8 __attribute__((ext_vector_type(8)));

static __device__ __forceinline__ short f2bf(float f) {
    return __builtin_bit_cast(short, (__bf16)f);
}
static __device__ __forceinline__ float bf2f(short s) {
    union { unsigned u; float f; } v;
    v.u = ((unsigned)(unsigned short)s) << 16;
    return v.f;
}
static __device__ __forceinline__ f32x4 MM(s16x8 a, s16x8 b, f32x4 c) {
    return __builtin_amdgcn_mfma_f32_16x16x32_bf16(
        __builtin_bit_cast(bf16x8, a), __builtin_bit_cast(bf16x8, b), c, 0, 0, 0);
}
#define KEEP(x) asm volatile("" : "+v"(x))

// ---------------------------------------------------------------------------
// K0: one-shot f32 -> bf16 conversion of all reused operands.
// ---------------------------------------------------------------------------
struct CvtArgs {
    const float* src[9];
    short* dst[9];
    unsigned n[9];
};

__global__ __launch_bounds__(256) void convert_kernel(CvtArgs a) {
    const int ai = blockIdx.y;
    const unsigned n = a.n[ai];
    const float* __restrict__ s = a.src[ai];
    short* __restrict__ d = a.dst[ai];
    const unsigned stride = gridDim.x * 256 * 8;
    for (unsigned base = (blockIdx.x * 256 + threadIdx.x) * 8; base < n; base += stride) {
        f32x4 v0 = *(const f32x4*)(s + base);
        f32x4 v1 = *(const f32x4*)(s + base + 4);
        s16x8 o;
        o[0] = f2bf(v0[0]); o[1] = f2bf(v0[1]); o[2] = f2bf(v0[2]); o[3] = f2bf(v0[3]);
        o[4] = f2bf(v1[0]); o[5] = f2bf(v1[1]); o[6] = f2bf(v1[2]); o[7] = f2bf(v1[3]);
        *(s16x8*)(d + base) = o;
    }
}

// ---------------------------------------------------------------------------
// K1: QKV projections, 64x64 wave tiles, swapped operands -> vector b64 stores.
// ---------------------------------------------------------------------------
__global__ __launch_bounds__(128, 2) void proj_kernel(
    const short* __restrict__ queryb, const short* __restrict__ keyb, const short* __restrict__ valueb,
    const short* __restrict__ Wqb, const float* __restrict__ bq,
    const short* __restrict__ Wkb, const float* __restrict__ bk,
    const short* __restrict__ Wvb, const float* __restrict__ bv,
    short* __restrict__ qb, short* __restrict__ kb, short* __restrict__ vT)
{
    const int tid = threadIdx.x;
    const int wid = tid >> 6, lane = tid & 63;
    const int l15 = lane & 15, grp = lane >> 4;
    const int gid = blockIdx.x * 2 + wid;     // 0..1535
    const int z = gid >> 9;                   // 0,1,2
    const int r = gid & 511;

    const short *Am, *Bm;
    const float* bias;
    int a0, b0;
    if (z == 0)      { Am = Wqb;    Bm = queryb; bias = bq; a0 = (r >> 6) * 64; b0 = (r & 63) * 64; }
    else if (z == 1) { Am = Wkb;    Bm = keyb;   bias = bk; a0 = (r >> 6) * 64; b0 = (r & 63) * 64; }
    else             { Am = valueb; Bm = Wvb;    bias = bv; a0 = (r >> 3) * 64; b0 = (r & 7) * 64; }

    f32x4 acc[4][4];
    #pragma unroll
    for (int i = 0; i < 4; ++i)
        #pragma unroll
        for (int j = 0; j < 4; ++j)
            acc[i][j] = f32x4{0.f, 0.f, 0.f, 0.f};

    const short* arow0 = Am + (size_t)(a0 + l15) * 512 + grp * 8;
    const short* brow0 = Bm + (size_t)(b0 + l15) * 512 + grp * 8;

    s16x8 aA[4], bA[4], aB[4], bB[4];
    #pragma unroll
    for (int i = 0; i < 4; ++i) {
        aA[i] = *(const s16x8*)(arow0 + (size_t)i * 16 * 512);
        bA[i] = *(const s16x8*)(brow0 + (size_t)i * 16 * 512);
    }
    for (int kk = 0; kk < 512; kk += 32) {
        const int kn = kk + 32;
        if (kn < 512) {
            #pragma unroll
            for (int i = 0; i < 4; ++i) {
                aB[i] = *(const s16x8*)(arow0 + (size_t)i * 16 * 512 + kn);
                bB[i] = *(const s16x8*)(brow0 + (size_t)i * 16 * 512 + kn);
            }
        }
        #pragma unroll
        for (int i = 0; i < 4; ++i)
            #pragma unroll
            for (int j = 0; j < 4; ++j)
                acc[i][j] = MM(aA[i], bA[j], acc[i][j]);
        #pragma unroll
        for (int i = 0; i < 4; ++i) { aA[i] = aB[i]; bA[i] = bB[i]; }
    }

    if (z < 2) {
        short* dst = (z == 0) ? qb : kb;
        #pragma unroll
        for (int i = 0; i < 4; ++i) {
            const int f0 = a0 + i * 16 + grp * 4;
            const f32x4 bv4 = *(const f32x4*)&bias[f0];
            const int h = f0 >> 6, d0 = f0 & 63;
            #pragma unroll
            for (int j = 0; j < 4; ++j) {
                const int srow = b0 + j * 16 + l15;
                const int bb = srow >> 10, sl = srow & 1023;
                s16x4 o;
                #pragma unroll
                for (int g = 0; g < 4; ++g)
                    o[g] = f2bf(acc[i][j][g] + bv4[g]);
                *(s16x4*)&dst[(size_t)((bb * 8 + h) * 1024 + sl) * 64 + d0] = o;
            }
        }
    } else {
        #pragma unroll
        for (int j = 0; j < 4; ++j) {
            const int n = b0 + j * 16 + l15;
            const float bval = bias[n];
            const int h = n >> 6, d = n & 63;
            #pragma unroll
            for (int i = 0; i < 4; ++i) {
                const int s0 = a0 + i * 16 + grp * 4;
                const int bb = s0 >> 10, sl = s0 & 1023;
                s16x4 o;
                #pragma unroll
                for (int g = 0; g < 4; ++g)
                    o[g] = f2bf(acc[i][j][g] + bval);
                *(s16x4*)&vT[(size_t)((bb * 8 + h) * 64 + d) * 1024 + sl] = o;
            }
        }
    }
}

// ---------------------------------------------------------------------------
// K2: persistent fused relative attention (R7 structure).
// Grid 256 x 512thr; block = (b,h, 128-row chunk), 8 strips of 16 rows.
// Thread (wid,grp,l15) holds P[i=l15][j = wid*128 + t*16 + grp*4 + g].
// LDS 155520B:
//   RQ2 x2 [16][1028] bf16 @ 0 / 32896
//   RB2 x2 [16][260]  bf16 @ 65792 / 74112
//   RR2 x2 [16][68]   bf16 @ 82432 / 84608
//   PS      [16][1028] bf16 @ 86784  (XOR-swizzled cols, unnormalized P)
//   PACC    [8][16][68] f32 @ 119680
//   RSUM x2 [16][8] f32     @ 154496 / 155008  (non-overlapping parity)
// ---------------------------------------------------------------------------
__global__ __launch_bounds__(512, 2) void attn_kernel(
    const short* __restrict__ Eqb, const short* __restrict__ Ebb, const short* __restrict__ Errb,
    const short* __restrict__ qb, const short* __restrict__ kb, const short* __restrict__ vT,
    float* __restrict__ out, float* __restrict__ attn)
{
    __shared__ __align__(16) char smem[155520];
    short* PS   = (short*)(smem + 86784);
    float* PACC = (float*)(smem + 119680);

    const int tid = threadIdx.x;
    const int wid = tid >> 6, lane = tid & 63;
    const int l15 = lane & 15, grp = lane >> 4;

    // XCD-aware bijective swizzle (256 blocks, %8==0): XCD x -> 4 whole bh.
    const int orig = blockIdx.x;
    const int bid = (orig & 7) * 32 + (orig >> 3);

    const int bh = bid >> 3;                 // b*8+h
    const int chunk = bid & 7;               // 128-row chunk
    const int h = bh & 7;
    const int b = bh >> 3;

    const short* EqH = Eqb  + (size_t)h * 2047 * 64;
    const short* EbH = Ebb  + (size_t)h * 511 * 64;
    const short* ErH = Errb + (size_t)h * 127 * 64;
    const short* qbH = qb + (size_t)bh * 1024 * 64;
    const short* kbH = kb + (size_t)bh * 1024 * 64;
    const short* vTH = vT + (size_t)bh * 64 * 1024;

    // ---- table builder: strip at i0s -> buffer bb01 (uses that strip's q) ----
    auto buildT = [&](int i0s, int bb01, s16x8 q0, s16x8 q1) {
        short* RQ2 = (short*)(smem + bb01 * 32896);
        short* RB2 = (short*)(smem + 65792 + bb01 * 8320);
        short* RR2 = (short*)(smem + 82432 + bb01 * 2176);
        const int qbase = 1008 - i0s;
        {
            auto ldq = [&](int cs, s16x8& e0, s16x8& e1) {
                int erow = qbase + cs * 16 + l15; if (erow > 2046) erow = 2046;
                const short* ep = EqH + (size_t)erow * 64 + grp * 8;
                e0 = *(const s16x8*)ep;
                e1 = *(const s16x8*)(ep + 32);
            };
            s16x8 A0, A1, B0, B1, C0, C1;
            ldq(wid, A0, A1);
            ldq(wid + 8, B0, B1);
            ldq(wid + 16, C0, C1);
            for (int cs = wid; cs < 65; cs += 8) {
                f32x4 a = f32x4{0.f, 0.f, 0.f, 0.f};
                a = MM(q0, A0, a);
                a = MM(q1, A1, a);
                A0 = B0; A1 = B1; B0 = C0; B1 = C1;
                ldq(cs + 24, C0, C1);             // clamped; tail loads unused
                const int c = cs * 16 + l15;
                #pragma unroll
                for (int g = 0; g < 4; ++g) {
                    const int ii = grp * 4 + g;
                    const int j = c - 15 + ii;
                    if (j >= 0 && j < 1024) RQ2[ii * 1028 + j] = f2bf(a[g]);
                }
            }
        }
        const int bbase = 252 - (i0s >> 2);
        {
            auto ldb = [&](int cs, s16x8& e0, s16x8& e1) {
                int erow = bbase + cs * 16 + l15; if (erow > 510) erow = 510;
                const short* ep = EbH + (size_t)erow * 64 + grp * 8;
                e0 = *(const s16x8*)ep;
                e1 = *(const s16x8*)(ep + 32);
            };
            s16x8 A0, A1, B0, B1;
            ldb(wid, A0, A1);
            ldb(wid + 8, B0, B1);
            for (int cs = wid; cs < 17; cs += 8) {
                f32x4 a = f32x4{0.f, 0.f, 0.f, 0.f};
                a = MM(q0, A0, a);
                a = MM(q1, A1, a);
                A0 = B0; A1 = B1;
                ldb(cs + 16, B0, B1);
                const int c = cs * 16 + l15;
                const int jq = c - 3 + grp;          // (ii>>2) == grp
                if (jq >= 0 && jq < 256) {
                    #pragma unroll
                    for (int g = 0; g < 4; ++g)
                        RB2[(grp * 4 + g) * 260 + jq] = f2bf(a[g]);
                }
            }
        }
        const int rbase = 63 - (i0s >> 4);
        if (wid < 4) {
            const int c = wid * 16 + l15;        // 0..63
            const short* ep = ErH + (size_t)(rbase + c) * 64 + grp * 8;
            s16x8 e0 = *(const s16x8*)ep;
            s16x8 e1 = *(const s16x8*)(ep + 32);
            f32x4 a = f32x4{0.f, 0.f, 0.f, 0.f};
            a = MM(q0, e0, a);
            a = MM(q1, e1, a);
            #pragma unroll
            for (int g = 0; g < 4; ++g)
                RR2[(grp * 4 + g) * 68 + c] = f2bf(a[g]);
        }
    };

    // ---- prologue: q(strip0), K fragments, V fragments ----
    const int i00 = chunk * 128;
    s16x8 qA0 = *(const s16x8*)(qbH + (size_t)(i00 + l15) * 64 + grp * 8);
    s16x8 qA1 = *(const s16x8*)(qbH + (size_t)(i00 + l15) * 64 + 32 + grp * 8);

    s16x8 kf[8][2];
    #pragma unroll
    for (int t = 0; t < 8; ++t) {
        const short* kp = kbH + (size_t)(wid * 128 + t * 16 + l15) * 64 + grp * 8;
        kf[t][0] = *(const s16x8*)kp;
        kf[t][1] = *(const s16x8*)(kp + 32);
    }
    s16x8 vreg[16];
    #pragma unroll
    for (int dvt = 0; dvt < 4; ++dvt)
        #pragma unroll
        for (int kc = 0; kc < 4; ++kc)
            vreg[dvt * 4 + kc] = *(const s16x8*)(vTH + (size_t)(dvt * 16 + l15) * 1024
                                                 + wid * 128 + kc * 32 + grp * 8);

    buildT(i00, 0, qA0, qA1);
    __syncthreads();

    const float SC = 0.125f * 1.4426950408889634f;   // 1/sqrt(64) * log2(e)
    const int swz = (l15 & 3) << 5;                  // PS col XOR swizzle

    for (int s = 0; s < 8; ++s) {
        // loop-carried pins: forbid rematerializing kf/vreg loads per strip
        #pragma unroll
        for (int t = 0; t < 8; ++t) { KEEP(kf[t][0]); KEEP(kf[t][1]); }
        #pragma unroll
        for (int z = 0; z < 16; ++z) KEEP(vreg[z]);

        const int cur = s & 1;
        const int i0 = chunk * 128 + s * 16;
        short* RQ2c = (short*)(smem + cur * 32896);
        short* RB2c = (short*)(smem + 65792 + cur * 8320);
        short* RR2c = (short*)(smem + 82432 + cur * 2176);
        float* RSUMc = (float*)(smem + 154496 + cur * 512);

        // prefetch next strip's q (feeds buildT after BAR1)
        s16x8 qn0, qn1;
        if (s < 7) {
            qn0 = *(const s16x8*)(qbH + (size_t)(i0 + 16 + l15) * 64 + grp * 8);
            qn1 = *(const s16x8*)(qbH + (size_t)(i0 + 16 + l15) * 64 + 32 + grp * 8);
        }

        // ---- QK^T (swapped) + gathers + exp2 -> p (unnormalized) ----
        f32x4 p[8];
        #pragma unroll
        for (int t = 0; t < 8; ++t) {
            f32x4 a = f32x4{0.f, 0.f, 0.f, 0.f};
            a = MM(kf[t][0], qA0, a);
            a = MM(kf[t][1], qA1, a);
            const int jb2 = wid * 128 + t * 16 + grp * 4;
            s16x4 gq4 = *(const s16x4*)&RQ2c[l15 * 1028 + jb2];
            const float rb = bf2f(RB2c[l15 * 260 + wid * 32 + t * 4 + grp]);
            const float rr = bf2f(RR2c[l15 * 68 + wid * 8 + t]);
            const float add = rb + rr;
            f32x4 pe;
            #pragma unroll
            for (int g = 0; g < 4; ++g)
                pe[g] = __builtin_amdgcn_exp2f((a[g] + bf2f(gq4[g]) + add) * SC);
            p[t] = pe;
        }

        // ---- in-thread row partial + cross-grp shuffle + RSUM ----
        float part = 0.f;
        #pragma unroll
        for (int t = 0; t < 8; ++t)
            #pragma unroll
            for (int g = 0; g < 4; ++g)
                part += p[t][g];
        part += __shfl_xor(part, 16, 64);
        part += __shfl_xor(part, 32, 64);
        if (lane < 16) RSUMc[lane * 8 + wid] = part;   // wave partial for row l15

        // ---- stage unnormalized bf16 P (vector b64, swizzled cols); p dies ----
        #pragma unroll
        for (int t = 0; t < 8; ++t) {
            const int col = (wid * 128 + t * 16 + grp * 4) ^ swz;
            s16x4 o;
            #pragma unroll
            for (int g = 0; g < 4; ++g) o[g] = f2bf(p[t][g]);
            *(s16x4*)&PS[l15 * 1028 + col] = o;
        }
        __syncthreads();                               // BAR1: PS + RSUM ready

        // ---- build next strip's tables (overlaps store + PV) ----
        if (s < 7) buildT(i0 + 16, cur ^ 1, qn0, qn1);

        // ---- attn store from PS: wave w -> rows 2w..2w+1, 1KB contiguous ----
        {
            const int r0 = wid * 2;
            #pragma unroll
            for (int k = 0; k < 2; ++k) {
                const int r = r0 + k;
                f32x4 s0 = *(const f32x4*)&RSUMc[r * 8];
                f32x4 s1 = *(const f32x4*)&RSUMc[r * 8 + 4];
                const float ri = 1.0f / (s0[0] + s0[1] + s0[2] + s0[3]
                                         + s1[0] + s1[1] + s1[2] + s1[3]);
                float* arow = attn + (size_t)(bh * 1024 + i0 + r) * 1024;
                const int rswz = (r & 3) << 5;
                #pragma unroll
                for (int pass = 0; pass < 4; ++pass) {
                    const int col = pass * 256 + lane * 4;
                    s16x4 v4 = *(const s16x4*)&PS[r * 1028 + (col ^ rswz)];
                    f32x4 o;
                    o[0] = bf2f(v4[0]) * ri; o[1] = bf2f(v4[1]) * ri;
                    o[2] = bf2f(v4[2]) * ri; o[3] = bf2f(v4[3]) * ri;
                    *(f32x4*)(arow + col) = o;
                }
            }
        }

        // ---- PV: O_partial[i][dv] over this wave's 128 k-cols ----
        f32x4 acc[4];
        #pragma unroll
        for (int dvt = 0; dvt < 4; ++dvt) acc[dvt] = f32x4{0.f, 0.f, 0.f, 0.f};
        #pragma unroll
        for (int kc = 0; kc < 4; ++kc) {
            const int col = (wid * 128 + kc * 32 + grp * 8) ^ swz;
            s16x8 bfrag = *(const s16x8*)&PS[l15 * 1028 + col];
            #pragma unroll
            for (int dvt = 0; dvt < 4; ++dvt)
                acc[dvt] = MM(vreg[dvt * 4 + kc], bfrag, acc[dvt]);
        }
        #pragma unroll
        for (int dvt = 0; dvt < 4; ++dvt)
            *(f32x4*)&PACC[(wid * 16 + l15) * 68 + dvt * 16 + grp * 4] = acc[dvt];
        __syncthreads();                               // BAR2: PACC + tables built

        // ---- out-reduce (waves 0-3): sum 8 wave-partials, scale by rinv ----
        if (tid < 256) {
            const int i = tid >> 4, dvq = tid & 15;
            f32x4 o = f32x4{0.f, 0.f, 0.f, 0.f};
            #pragma unroll
            for (int w = 0; w < 8; ++w)
                o += *(const f32x4*)&PACC[(w * 16 + i) * 68 + dvq * 4];
            f32x4 s0 = *(const f32x4*)&RSUMc[i * 8];
            f32x4 s1 = *(const f32x4*)&RSUMc[i * 8 + 4];
            const float ri = 1.0f / (s0[0] + s0[1] + s0[2] + s0[3]
                                     + s1[0] + s1[1] + s1[2] + s1[3]);
            o *= ri;
            *(f32x4*)&out[(size_t)(b * 1024 + i0 + i) * 512 + h * 64 + dvq * 4] = o;
        }

        if (s < 7) { qA0 = qn0; qA1 = qn1; }
    }
}

// ---------------------------------------------------------------------------
extern "C" void kernel_launch(void* const* d_in, const int* in_sizes, int n_in,
                              void* d_out, int out_size, void* d_ws, size_t ws_size,
                              hipStream_t stream)
{
    const float* query = (const float*)d_in[0];
    const float* key   = (const float*)d_in[1];
    const float* value = (const float*)d_in[2];
    const float* Wq = (const float*)d_in[3];
    const float* bq = (const float*)d_in[4];
    const float* Wk = (const float*)d_in[5];
    const float* bk = (const float*)d_in[6];
    const float* Wv = (const float*)d_in[7];
    const float* bv = (const float*)d_in[8];
    const float* Eq = (const float*)d_in[9];
    const float* Eb = (const float*)d_in[10];
    const float* Er = (const float*)d_in[11];

    float* out  = (float*)d_out;
    float* attn = out + (size_t)4 * 1024 * 512;

    short* qb     = (short*)d_ws;
    short* kb     = qb     + 2097152;
    short* vT     = kb     + 2097152;
    short* queryb = vT     + 2097152;
    short* keyb   = queryb + 2097152;
    short* valueb = keyb   + 2097152;
    short* Wqb    = valueb + 2097152;
    short* Wkb    = Wqb    + 262144;
    short* Wvb    = Wkb    + 262144;
    short* Eqb    = Wvb    + 262144;
    short* Ebb    = Eqb    + 1048064;   // 8*2047*64
    short* Errb   = Ebb    + 261632;    // 8*511*64

    CvtArgs a;
    a.src[0] = query; a.dst[0] = queryb; a.n[0] = 2097152;
    a.src[1] = key;   a.dst[1] = keyb;   a.n[1] = 2097152;
    a.src[2] = value; a.dst[2] = valueb; a.n[2] = 2097152;
    a.src[3] = Wq;    a.dst[3] = Wqb;    a.n[3] = 262144;
    a.src[4] = Wk;    a.dst[4] = Wkb;    a.n[4] = 262144;
    a.src[5] = Wv;    a.dst[5] = Wvb;    a.n[5] = 262144;
    a.src[6] = Eq;    a.dst[6] = Eqb;    a.n[6] = 1048064;
    a.src[7] = Eb;    a.dst[7] = Ebb;    a.n[7] = 261632;
    a.src[8] = Er;    a.dst[8] = Errb;   a.n[8] = 65024;

    convert_kernel<<<dim3(1024, 9), 256, 0, stream>>>(a);
    proj_kernel<<<768, 128, 0, stream>>>(queryb, keyb, valueb,
                                         Wqb, bq, Wkb, bk, Wvb, bv, qb, kb, vT);
    attn_kernel<<<256, 512, 0, stream>>>(Eqb, Ebb, Errb, qb, kb, vT, out, attn);
}